// Round 7
// baseline (19486.949 us; speedup 1.0000x reference)
//
#include <hip/hip_runtime.h>
#include <hip/hip_cooperative_groups.h>

namespace cg = cooperative_groups;

#define TT 256
#define BDIM 512
#define GRID 256

typedef unsigned short u16;
typedef unsigned int u32;
typedef __attribute__((ext_vector_type(8))) short bf16x8;
typedef __attribute__((ext_vector_type(4))) float f32x4;

// async global->LDS, 16B/lane; LDS dest is wave-uniform base + lane*16
#define GLL(g, l) __builtin_amdgcn_global_load_lds( \
    (const __attribute__((address_space(1))) void*)(g), \
    (__attribute__((address_space(3))) void*)(l), 16, 0, 0)

struct P {
  const float* obs; const float* action; const int* is_first;
  const float* w_prior_in; const float* g_prior_in; const float* bb_prior_in;
  const float* w_gru; const float* g_gru; const float* bb_gru;
  const float* w_prior_out; const float* g_prior_out; const float* bb_prior_out;
  const float* w_prior_stats; const float* b_prior_stats;
  const float* w_post; const float* g_post; const float* bb_post;
  const float* w_post_stats; const float* b_post_stats;
  const float* initial_deter;
  float* out;
  // 2-plane weights, UNSWIZZLED chunk images for direct global->VGPR fragment loads.
  // image (one 32-k chunk) = [hi: R rows x 32k | lo: R rows x 32k] u16, row-major.
  u16 *WgT3;    // 192 images (pc*6+np), R=256, K-order [deter512|h512]
  u16 *W2T3;    // 68  images (pc*4+np), R=256, K-order [deter512|obs32]
  u16 *WsT3;    // 32  images (pc),      R=128, K = h2(1024)
  float *wpiT;  // [512][36] transposed w_prior_in
  float *deter0, *init_mean;
  int *segb, *segt0, *nact;
  u16 *dslot;   // [2048 tiles][32768] deter 2-plane swizzled chunks (verbatim LDS format)
  float *sslot; // [2048 tiles][1024] stoch fp32
};

__device__ __forceinline__ float b2f(u16 u) {
  union { float f; u32 i; } v; v.i = ((u32)u) << 16; return v.f;
}
__device__ __forceinline__ u16 f2b(float f) {
  union { float f; u32 i; } v; v.f = f;
  u32 r = v.i + 0x7FFF + ((v.i >> 16) & 1);   // RNE
  return (u16)(r >> 16);
}
__device__ __forceinline__ float sigm(float x) { return 1.f / (1.f + __expf(-x)); }
__device__ __forceinline__ float splus(float x) { return x > 15.f ? x : log1pf(__expf(x)); }

// write hi/lo planes of logical (row i, col kk) into a 2-plane swizzled chunk buffer
__device__ __forceinline__ void awr2(u16* base, int i, int kk, u16 hi, u16 lo) {
  int o = (kk >> 5) << 11;
  int sw = ((i << 5) + (kk & 31)) ^ ((i & 7) << 3);
  base[o + sw] = hi;
  base[o + 1024 + sw] = lo;
}

// ---- prior_in head: h = silu(ln(x @ Wpi)); writes h planes (arow cols 544..1055) ----
__device__ __forceinline__ void h_from_x(const P& p, u16* arow, int i, float xv, int lane) {
  float xs[36];
  #pragma unroll
  for (int j = 0; j < 36; ++j) xs[j] = __shfl(xv, j, 64);
  float a0[8];
  #pragma unroll
  for (int c = 0; c < 8; ++c) {
    const float4* wp = (const float4*)(p.wpiT + (size_t)(lane + (c << 6)) * 36);
    float s = 0.f;
    #pragma unroll
    for (int t4 = 0; t4 < 9; ++t4) {
      float4 ww = wp[t4];
      s = fmaf(xs[4 * t4], ww.x, s); s = fmaf(xs[4 * t4 + 1], ww.y, s);
      s = fmaf(xs[4 * t4 + 2], ww.z, s); s = fmaf(xs[4 * t4 + 3], ww.w, s);
    }
    a0[c] = s;
  }
  float sm = 0.f, sq = 0.f;
  #pragma unroll
  for (int c = 0; c < 8; ++c) { sm += a0[c]; sq += a0[c] * a0[c]; }
  #pragma unroll
  for (int o = 32; o; o >>= 1) { sm += __shfl_xor(sm, o); sq += __shfl_xor(sq, o); }
  float m = sm * (1.f / 512.f);
  float rs = rsqrtf(sq * (1.f / 512.f) - m * m + 1e-3f);
  #pragma unroll
  for (int c = 0; c < 8; ++c) {
    int col = lane + (c << 6);
    float v = (a0[c] - m) * rs * p.g_prior_in[col] + p.bb_prior_in[col];
    v = v * sigm(v);
    u16 hi = f2b(v);
    awr2(arow, i, 544 + col, hi, f2b(v - b2f(hi)));
  }
}

// ================= prep kernels =================
__global__ void k_weights(P p) {
  const int E1 = 1024 * 1536, E2 = 544 * 1024, E3 = 1024 * 128, E4 = 36 * 512;
  const int total = E1 + E2 + E3 + E4;
  for (int idx = blockIdx.x * blockDim.x + threadIdx.x; idx < total;
       idx += gridDim.x * blockDim.x) {
    if (idx < E1) {                        // Wg
      int k = idx / 1536, n = idx - k * 1536;
      float w = (k < 512) ? p.w_gru[(512 + k) * 1536 + n] : p.w_gru[(k - 512) * 1536 + n];
      int np = n >> 8, r = n & 255, pc = k >> 5, kk = k & 31;
      u16* d = p.WgT3 + ((size_t)(pc * 6 + np) << 14) + (r << 5) + kk;
      u16 hi = f2b(w); d[0] = hi; d[8192] = f2b(w - b2f(hi));
    } else if (idx < E1 + E2) {            // W2
      int t = idx - E1; int k = t >> 10, n = t & 1023;
      float w;
      if (k < 512) w = (n < 512) ? p.w_prior_out[k * 512 + n] : p.w_post[k * 512 + (n - 512)];
      else { int j = k - 512; w = (n >= 512 && j < 18) ? p.w_post[(512 + j) * 512 + (n - 512)] : 0.f; }
      int np = n >> 8, r = n & 255, pc = k >> 5, kk = k & 31;
      u16* d = p.W2T3 + ((size_t)(pc * 4 + np) << 14) + (r << 5) + kk;
      u16 hi = f2b(w); d[0] = hi; d[8192] = f2b(w - b2f(hi));
    } else if (idx < E1 + E2 + E3) {       // Ws
      int t = idx - E1 - E2; int k = t >> 7, n = t & 127;
      float w;
      if (n < 64) w = (k < 512) ? p.w_prior_stats[k * 64 + n] : 0.f;
      else        w = (k >= 512) ? p.w_post_stats[(k - 512) * 64 + (n - 64)] : 0.f;
      int pc = k >> 5, kk = k & 31;
      u16* d = p.WsT3 + ((size_t)pc << 13) + (n << 5) + kk;
      u16 hi = f2b(w); d[0] = hi; d[4096] = f2b(w - b2f(hi));
    } else {                               // wpiT transpose
      int t = idx - E1 - E2 - E3; int j = t >> 9, col = t & 511;
      p.wpiT[col * 36 + j] = p.w_prior_in[j * 512 + col];
    }
  }
}

__global__ void k_init_state(P p) {
  __shared__ float d0s[512], tmp[512], red[256];
  int tid = threadIdx.x;
  for (int n = tid; n < 512; n += 256) { d0s[n] = tanhf(p.initial_deter[n]); p.deter0[n] = d0s[n]; }
  __syncthreads();
  for (int n = tid; n < 512; n += 256) {
    float s = 0.f;
    for (int d = 0; d < 512; ++d) s = fmaf(d0s[d], p.w_prior_out[d * 512 + n], s);
    tmp[n] = s;
  }
  __syncthreads();
  float ls = 0.f, lq = 0.f;
  for (int n = tid; n < 512; n += 256) { ls += tmp[n]; lq += tmp[n] * tmp[n]; }
  red[tid] = ls; __syncthreads();
  for (int s = 128; s; s >>= 1) { if (tid < s) red[tid] += red[tid + s]; __syncthreads(); }
  float m = red[0] * (1.f / 512.f); __syncthreads();
  red[tid] = lq; __syncthreads();
  for (int s = 128; s; s >>= 1) { if (tid < s) red[tid] += red[tid + s]; __syncthreads(); }
  float rs = rsqrtf(red[0] * (1.f / 512.f) - m * m + 1e-3f); __syncthreads();
  for (int n = tid; n < 512; n += 256) {
    float h = (tmp[n] - m) * rs * p.g_prior_out[n] + p.bb_prior_out[n];
    tmp[n] = h * sigm(h);
  }
  __syncthreads();
  if (tid < 32) {
    float s = 0.f;
    for (int d = 0; d < 512; ++d) s = fmaf(tmp[d], p.w_prior_stats[d * 64 + tid], s);
    p.init_mean[tid] = s + p.b_prior_stats[tid];
  }
}

__global__ void k_segments(P p) {
  __shared__ int hist[257], off[258], cur[257];
  int tid = threadIdx.x;
  for (int i = tid; i < 257; i += 256) hist[i] = 0;
  __syncthreads();
  int b = tid;
  { int t = 0;
    while (t < TT) {
      int t0 = t; t++;
      while (t < TT && p.is_first[b * TT + t] == 0) t++;
      atomicAdd(&hist[t - t0], 1);
    } }
  __syncthreads();
  if (tid == 0) {
    int run = 0;
    for (int len = 256; len >= 0; --len) { off[len] = run; run += hist[len]; }
  }
  __syncthreads();
  for (int i = tid; i < 257; i += 256) { cur[i] = off[i]; p.nact[i] = off[i]; }
  __syncthreads();
  { int t = 0;
    while (t < TT) {
      int t0 = t; t++;
      while (t < TT && p.is_first[b * TT + t] == 0) t++;
      int idx = atomicAdd(&cur[t - t0], 1);
      p.segb[idx] = b; p.segt0[idx] = t0;
    } }
}

// ---- barrier-free GEMM pass: C(32 x NI*16 per wave) += A(LDS) * W^T ----
// W fragments global->VGPR, 4-set rotation (cover 3 steps); 8 waves.
template<int NI, int NSTEPS, int JAT>
__device__ __forceinline__ void gemm_nb(
    const u16* aLds, const u16* __restrict__ wBase, int wStrideU16,
    int wave, int quad, int l15, int xr, f32x4 (&acc)[2][NI]) {
  const u16* wq = wBase + (((wave * (NI * 16) + l15) << 5) + (quad << 3));
  bf16x8 H[4][NI], L[4][NI];
  auto ld = [&](int st, int s) {
    const u16* q = wq + (size_t)st * wStrideU16;
    #pragma unroll
    for (int ni = 0; ni < NI; ++ni) {
      H[s][ni] = *(const bf16x8*)(q + (ni << 9));
      L[s][ni] = *(const bf16x8*)(q + 8192 + (ni << 9));
    }
  };
  auto cp = [&](int st, int s) {
    int apc = st + (st >= JAT ? 1 : 0);
    const u16* A = aLds + (apc << 11);
    bf16x8 ah[2], al[2];
    #pragma unroll
    for (int mi = 0; mi < 2; ++mi) {
      int off = ((((mi << 4) + l15) << 5) + (quad << 3)) ^ xr;
      ah[mi] = *(const bf16x8*)&A[off];
      al[mi] = *(const bf16x8*)&A[off + 1024];
    }
    #pragma unroll
    for (int ni = 0; ni < NI; ++ni)
      #pragma unroll
      for (int mi = 0; mi < 2; ++mi) {
        acc[mi][ni] = __builtin_amdgcn_mfma_f32_16x16x32_bf16(ah[mi], H[s][ni], acc[mi][ni], 0, 0, 0);
        acc[mi][ni] = __builtin_amdgcn_mfma_f32_16x16x32_bf16(al[mi], H[s][ni], acc[mi][ni], 0, 0, 0);
        acc[mi][ni] = __builtin_amdgcn_mfma_f32_16x16x32_bf16(ah[mi], L[s][ni], acc[mi][ni], 0, 0, 0);
      }
  };
  ld(0, 0); ld(1, 1); ld(2, 2);
  #pragma unroll
  for (int st = 0; st < NSTEPS; ++st) {
    if (st + 3 < NSTEPS) ld(st + 3, (st + 3) & 3);
    cp(st, st & 3);
  }
}

// ================= cooperative main: grid-synced k-waves, block-owned tiles =================
__global__ void __launch_bounds__(BDIM, 1) k_main(P p) {
  cg::grid_group grid = cg::this_grid();
  __shared__ u16 arow[67584];         // 33 chunks x 2048 u16: deter pc0-15, obs pc16, h pc17-32
  __shared__ float lnscr[8][32][4];
  __shared__ int orowt[32];
  const int tid = threadIdx.x;
  const int wave = tid >> 6, lane = tid & 63, quad = lane >> 4, l15 = lane & 15;
  const int xr = (l15 & 7) << 3;
  u16* h2l = arow + 34816;            // phase E/F: 32 single-plane chunks x 1024 u16
  const int blk = blockIdx.x;

  for (int k = 0;; ++k) {
    int na = p.nact[k];               // uniform across grid
    if (na <= 0) break;
    int Tk = (na + 31) >> 5;
    for (int t = blk; t < Tk; t += GRID) {
      int row0 = t << 5;
      int Mk = na - row0; if (Mk > 32) Mk = 32;
      u16* dslot = p.dslot + ((size_t)t << 15);
      float* sslot = p.sslot + ((size_t)t << 10);

      // ---- load deter state (k>0): 64 KB verbatim into deter chunks ----
      if (k > 0) {
        #pragma unroll
        for (int r = 0; r < 8; ++r) {
          int o = ((r << 3) + wave) << 9;
          GLL(dslot + o + (lane << 3), (u16*)arow + o);
        }
      }
      if (tid < 32)
        orowt[tid] = (tid < Mk) ? (p.segb[row0 + tid] * TT + p.segt0[row0 + tid] + k) : -1;
      __syncthreads();   // drains GLL (vmcnt) + orowt visible

      // ---- A: state init (k==0) + obs planes + prior_in head ----
      for (int i = wave; i < Mk; i += 8) {
        int gi = row0 + i;
        int b = p.segb[gi], t0 = p.segt0[gi];
        float xv = 0.f;
        if (k == 0) {
          #pragma unroll
          for (int c = 0; c < 8; ++c) {
            int d = lane + (c << 6);
            float v = p.deter0[d];
            u16 hi = f2b(v);
            awr2(arow, i, d, hi, f2b(v - b2f(hi)));
          }
          int ff = p.is_first[b * TT + t0];
          if (lane < 32) xv = p.init_mean[lane];
          else if (lane < 36) xv = (ff > 0) ? 0.f : p.action[((size_t)b * TT + t0) * 4 + (lane - 32)];
        } else {
          if (lane < 32) xv = sslot[(i << 5) + lane];
          else if (lane < 36) xv = p.action[((size_t)b * TT + t0 + k) * 4 + (lane - 32)];
        }
        int tc = t0 + k;
        if (lane < 32) {
          float ov = (lane < 18) ? p.obs[((size_t)b * TT + tc) * 18 + lane] : 0.f;
          u16 hi = f2b(ov);
          awr2(arow, i, 512 + lane, hi, f2b(ov - b2f(hi)));
        }
        h_from_x(p, arow, i, xv, lane);
      }
      __syncthreads();

      // ---- B: gates = arow[deter|h] @ Wg  (6 passes, K=1024, barrier-free) ----
      f32x4 acc[6][2][2];
      #pragma unroll
      for (int np = 0; np < 6; ++np) {
        #pragma unroll
        for (int mi = 0; mi < 2; ++mi)
          #pragma unroll
          for (int ni = 0; ni < 2; ++ni) acc[np][mi][ni] = f32x4{0.f, 0.f, 0.f, 0.f};
        gemm_nb<2, 32, 16>(arow, p.WgT3 + np * 16384, 6 * 16384,
                           wave, quad, l15, xr, acc[np]);
      }
      __syncthreads();   // all waves done reading deter/h planes

      // ---- C (fused): cross-wave LN(gates) -> GRU -> deter planes (LDS+slot) + out ----
      {
        float smv[2][4], sqv[2][4];
        #pragma unroll
        for (int mi = 0; mi < 2; ++mi)
          #pragma unroll
          for (int rg = 0; rg < 4; ++rg) { smv[mi][rg] = 0.f; sqv[mi][rg] = 0.f; }
        #pragma unroll
        for (int np = 0; np < 6; ++np)
          #pragma unroll
          for (int mi = 0; mi < 2; ++mi)
            #pragma unroll
            for (int ni = 0; ni < 2; ++ni)
              #pragma unroll
              for (int rg = 0; rg < 4; ++rg) {
                float v = acc[np][mi][ni][rg];
                smv[mi][rg] += v; sqv[mi][rg] += v * v;
              }
        #pragma unroll
        for (int mi = 0; mi < 2; ++mi)
          #pragma unroll
          for (int rg = 0; rg < 4; ++rg) {
            float s = smv[mi][rg], qv = sqv[mi][rg];
            #pragma unroll
            for (int o = 1; o < 16; o <<= 1) { s += __shfl_xor(s, o); qv += __shfl_xor(qv, o); }
            smv[mi][rg] = s; sqv[mi][rg] = qv;
          }
        if (l15 == 0) {
          #pragma unroll
          for (int mi = 0; mi < 2; ++mi)
            #pragma unroll
            for (int rg = 0; rg < 4; ++rg) {
              int row = (mi << 4) + (quad << 2) + rg;
              lnscr[wave][row][0] = smv[mi][rg];
              lnscr[wave][row][1] = sqv[mi][rg];
            }
        }
        __syncthreads();
        #pragma unroll
        for (int mi = 0; mi < 2; ++mi)
          #pragma unroll
          for (int rg = 0; rg < 4; ++rg) {
            int row = (mi << 4) + (quad << 2) + rg;
            float a0 = 0.f, a1 = 0.f;
            #pragma unroll
            for (int w2 = 0; w2 < 8; ++w2) { a0 += lnscr[w2][row][0]; a1 += lnscr[w2][row][1]; }
            float m_ = a0 * (1.f / 1536.f);
            smv[mi][rg] = m_;
            sqv[mi][rg] = rsqrtf(a1 * (1.f / 1536.f) - m_ * m_ + 1e-3f);
          }
        #pragma unroll
        for (int hh = 0; hh < 2; ++hh)
          #pragma unroll
          for (int ni = 0; ni < 2; ++ni) {
            int dcol = (hh << 8) + (wave << 5) + (ni << 4) + l15;
            float gR = p.g_gru[dcol], gC = p.g_gru[512 + dcol], gU = p.g_gru[1024 + dcol];
            float bR = p.bb_gru[dcol], bC = p.bb_gru[512 + dcol], bU = p.bb_gru[1024 + dcol];
            int pcD = dcol >> 5, kkD = dcol & 31;
            #pragma unroll
            for (int mi = 0; mi < 2; ++mi)
              #pragma unroll
              for (int rg = 0; rg < 4; ++rg) {
                int row = (mi << 4) + (quad << 2) + rg;
                float m_ = smv[mi][rg], rs_ = sqv[mi][rg];
                float vr = (acc[hh][mi][ni][rg] - m_) * rs_ * gR + bR;
                float vc = (acc[2 + hh][mi][ni][rg] - m_) * rs_ * gC + bC;
                float vu = (acc[4 + hh][mi][ni][rg] - m_) * rs_ * gU + bU;
                float r_ = sigm(vr), u_ = sigm(vu - 1.f);
                float rc = r_ * vc, cand = rc * sigm(rc);
                int ab = (pcD << 11) + (((row << 5) + kkD) ^ ((row & 7) << 3));
                float dp = b2f(arow[ab]) + b2f(arow[ab + 1024]);
                float dn = u_ * cand + (1.f - u_) * dp;
                u16 hi = f2b(dn), lo = f2b(dn - b2f(hi));
                arow[ab] = hi; arow[ab + 1024] = lo;
                dslot[ab] = hi; dslot[ab + 1024] = lo;
                int ot = orowt[row];
                if (ot >= 0) {
                  float* orow = p.out + (size_t)ot * 1216;
                  orow[dcol] = dn; orow[608 + dcol] = dn;
                }
              }
          }
      }
      __syncthreads();

      // ---- D: hraw = arow[deter|obs] @ W2  (4 passes, K=544, barrier-free) ----
      f32x4 dac[4][2][2];
      #pragma unroll
      for (int np = 0; np < 4; ++np) {
        #pragma unroll
        for (int mi = 0; mi < 2; ++mi)
          #pragma unroll
          for (int ni = 0; ni < 2; ++ni) dac[np][mi][ni] = f32x4{0.f, 0.f, 0.f, 0.f};
        gemm_nb<2, 17, 100>(arow, p.W2T3 + np * 16384, 4 * 16384,
                            wave, quad, l15, xr, dac[np]);
      }

      // ---- E (fused): two cross-wave LNs + silu -> h2 single-plane into LDS ----
      {
        float sP[2][4], qP[2][4], sQ[2][4], qQ[2][4];
        #pragma unroll
        for (int mi = 0; mi < 2; ++mi)
          #pragma unroll
          for (int rg = 0; rg < 4; ++rg) { sP[mi][rg]=0.f; qP[mi][rg]=0.f; sQ[mi][rg]=0.f; qQ[mi][rg]=0.f; }
        #pragma unroll
        for (int np = 0; np < 4; ++np)
          #pragma unroll
          for (int mi = 0; mi < 2; ++mi)
            #pragma unroll
            for (int ni = 0; ni < 2; ++ni)
              #pragma unroll
              for (int rg = 0; rg < 4; ++rg) {
                float v = dac[np][mi][ni][rg];
                if (np < 2) { sP[mi][rg] += v; qP[mi][rg] += v * v; }
                else        { sQ[mi][rg] += v; qQ[mi][rg] += v * v; }
              }
        #pragma unroll
        for (int mi = 0; mi < 2; ++mi)
          #pragma unroll
          for (int rg = 0; rg < 4; ++rg) {
            float a0 = sP[mi][rg], a1 = qP[mi][rg], a2 = sQ[mi][rg], a3 = qQ[mi][rg];
            #pragma unroll
            for (int o = 1; o < 16; o <<= 1) {
              a0 += __shfl_xor(a0, o); a1 += __shfl_xor(a1, o);
              a2 += __shfl_xor(a2, o); a3 += __shfl_xor(a3, o);
            }
            sP[mi][rg] = a0; qP[mi][rg] = a1; sQ[mi][rg] = a2; qQ[mi][rg] = a3;
          }
        if (l15 == 0) {
          #pragma unroll
          for (int mi = 0; mi < 2; ++mi)
            #pragma unroll
            for (int rg = 0; rg < 4; ++rg) {
              int row = (mi << 4) + (quad << 2) + rg;
              lnscr[wave][row][0] = sP[mi][rg]; lnscr[wave][row][1] = qP[mi][rg];
              lnscr[wave][row][2] = sQ[mi][rg]; lnscr[wave][row][3] = qQ[mi][rg];
            }
        }
        __syncthreads();   // all waves finished D; h-region rewrite now safe
        float mP[2][4], rP[2][4], mQ[2][4], rQ[2][4];
        #pragma unroll
        for (int mi = 0; mi < 2; ++mi)
          #pragma unroll
          for (int rg = 0; rg < 4; ++rg) {
            int row = (mi << 4) + (quad << 2) + rg;
            float a0 = 0.f, a1 = 0.f, a2 = 0.f, a3 = 0.f;
            #pragma unroll
            for (int w2 = 0; w2 < 8; ++w2) {
              a0 += lnscr[w2][row][0]; a1 += lnscr[w2][row][1];
              a2 += lnscr[w2][row][2]; a3 += lnscr[w2][row][3];
            }
            mP[mi][rg] = a0 * (1.f / 512.f);
            rP[mi][rg] = rsqrtf(a1 * (1.f / 512.f) - mP[mi][rg] * mP[mi][rg] + 1e-3f);
            mQ[mi][rg] = a2 * (1.f / 512.f);
            rQ[mi][rg] = rsqrtf(a3 * (1.f / 512.f) - mQ[mi][rg] * mQ[mi][rg] + 1e-3f);
          }
        #pragma unroll
        for (int np = 0; np < 4; ++np) {
          const int half = np >> 1;
          #pragma unroll
          for (int ni = 0; ni < 2; ++ni) {
            int col = (np << 8) + (wave << 5) + (ni << 4) + l15;
            int c5 = col & 511;
            float gv = half ? p.g_post[c5] : p.g_prior_out[c5];
            float bv = half ? p.bb_post[c5] : p.bb_prior_out[c5];
            int pcH = col >> 5, kkH = col & 31;
            #pragma unroll
            for (int mi = 0; mi < 2; ++mi)
              #pragma unroll
              for (int rg = 0; rg < 4; ++rg) {
                int row = (mi << 4) + (quad << 2) + rg;
                float m_ = half ? mQ[mi][rg] : mP[mi][rg];
                float rs_ = half ? rQ[mi][rg] : rP[mi][rg];
                float xx = (dac[np][mi][ni][rg] - m_) * rs_ * gv + bv;
                xx = xx * sigm(xx);
                h2l[(pcH << 10) + (((row << 5) + kkH) ^ ((row & 7) << 3))] = f2b(xx);
              }
          }
        }
      }
      __syncthreads();   // h2 in LDS visible to all waves

      // ---- F: stats = h2l @ Ws (32 steps, LDS A single-plane, reg W 4-set) ----
      {
        const u16* wqF = p.WsT3 + (((wave << 4) + l15) << 5) + (quad << 3);
        f32x4 fac[2];
        fac[0] = f32x4{0.f, 0.f, 0.f, 0.f};
        fac[1] = f32x4{0.f, 0.f, 0.f, 0.f};
        bf16x8 FH[4], FL[4];
        auto ldF = [&](int st, int s) {
          const u16* q = wqF + (st << 13);
          FH[s] = *(const bf16x8*)(q);
          FL[s] = *(const bf16x8*)(q + 4096);
        };
        auto cpF = [&](int st, int s) {
          const u16* A = h2l + (st << 10);
          #pragma unroll
          for (int mi = 0; mi < 2; ++mi) {
            int off = ((((mi << 4) + l15) << 5) + (quad << 3)) ^ xr;
            bf16x8 ah = *(const bf16x8*)&A[off];
            fac[mi] = __builtin_amdgcn_mfma_f32_16x16x32_bf16(ah, FH[s], fac[mi], 0, 0, 0);
            fac[mi] = __builtin_amdgcn_mfma_f32_16x16x32_bf16(ah, FL[s], fac[mi], 0, 0, 0);
          }
        };
        ldF(0, 0); ldF(1, 1); ldF(2, 2);
        #pragma unroll
        for (int st = 0; st < 32; ++st) {
          if (st + 3 < 32) ldF(st + 3, (st + 3) & 3);
          cpF(st, st & 3);
        }
        #pragma unroll
        for (int mi = 0; mi < 2; ++mi)
          #pragma unroll
          for (int rg = 0; rg < 4; ++rg) {
            int i = (mi << 4) + (quad << 2) + rg;
            int col = (wave << 4) + l15;
            if (i < Mk) {
              float v = fac[mi][rg];
              int ot = orowt[i];
              float* orow = p.out + (size_t)ot * 1216;
              if (col < 32) {
                v += p.b_prior_stats[col];
                orow[1120 + col] = v; orow[1152 + col] = v;
              } else if (col < 64) {
                v = splus(v + p.b_prior_stats[col]) + 0.1f;
                orow[1184 + col - 32] = v;
              } else if (col < 96) {
                v += p.b_post_stats[col - 64];
                orow[512 + col - 64] = v; orow[544 + col - 64] = v;
                sslot[(i << 5) + (col - 64)] = v;
              } else {
                v = splus(v + p.b_post_stats[col - 64]) + 0.1f;
                orow[576 + col - 96] = v;
              }
            }
          }
      }
      __syncthreads();   // drains sslot/dslot stores before next tile / next k
    }
    grid.sync();         // phase-align the weight stream across the grid
  }
}

extern "C" void kernel_launch(void* const* d_in, const int* in_sizes, int n_in,
                              void* d_out, int out_size, void* d_ws, size_t ws_size,
                              hipStream_t stream) {
  P p;
  p.obs = (const float*)d_in[0];
  p.action = (const float*)d_in[1];
  p.is_first = (const int*)d_in[2];
  p.w_prior_in = (const float*)d_in[3];
  p.g_prior_in = (const float*)d_in[4];
  p.bb_prior_in = (const float*)d_in[5];
  p.w_gru = (const float*)d_in[6];
  p.g_gru = (const float*)d_in[7];
  p.bb_gru = (const float*)d_in[8];
  p.w_prior_out = (const float*)d_in[9];
  p.g_prior_out = (const float*)d_in[10];
  p.bb_prior_out = (const float*)d_in[11];
  p.w_prior_stats = (const float*)d_in[12];
  p.b_prior_stats = (const float*)d_in[13];
  p.w_post = (const float*)d_in[14];
  p.g_post = (const float*)d_in[15];
  p.bb_post = (const float*)d_in[16];
  p.w_post_stats = (const float*)d_in[17];
  p.b_post_stats = (const float*)d_in[18];
  p.initial_deter = (const float*)d_in[19];
  p.out = (float*)d_out;

  char* w = (char*)d_ws;
  auto alloc = [&](size_t bytes) -> char* {
    char* r = w; w += (bytes + 255) & ~(size_t)255; return r;
  };
  p.WgT3 = (u16*)alloc((size_t)192 * 16384 * 2);
  p.W2T3 = (u16*)alloc((size_t)68 * 16384 * 2);
  p.WsT3 = (u16*)alloc((size_t)32 * 8192 * 2);
  p.wpiT = (float*)alloc((size_t)512 * 36 * 4);
  p.deter0 = (float*)alloc(512 * 4);
  p.init_mean = (float*)alloc(32 * 4);
  p.segb = (int*)alloc((size_t)65536 * 4);
  p.segt0 = (int*)alloc((size_t)65536 * 4);
  p.nact = (int*)alloc(257 * 4);
  p.dslot = (u16*)alloc((size_t)2048 * 32768 * 2);   // 134 MB: covers ntiles <= 2048
  p.sslot = (float*)alloc((size_t)2048 * 1024 * 4);  // 8.4 MB

  k_weights<<<dim3(256), dim3(256), 0, stream>>>(p);
  k_init_state<<<dim3(1), dim3(256), 0, stream>>>(p);
  k_segments<<<dim3(1), dim3(256), 0, stream>>>(p);
  void* args[] = { &p };
  hipLaunchCooperativeKernel(reinterpret_cast<void*>(&k_main), dim3(GRID), dim3(BDIM),
                             args, 0, stream);
}

// Round 8
// 8745.187 us; speedup vs baseline: 2.2283x; 2.2283x over previous
//
#include <hip/hip_runtime.h>

#define TT 256
#define BDIM 512
#define GRID 256

typedef unsigned short u16;
typedef unsigned int u32;
typedef __attribute__((ext_vector_type(8))) short bf16x8;
typedef __attribute__((ext_vector_type(4))) float f32x4;

struct P {
  const float* obs; const float* action; const int* is_first;
  const float* w_prior_in; const float* g_prior_in; const float* bb_prior_in;
  const float* w_gru; const float* g_gru; const float* bb_gru;
  const float* w_prior_out; const float* g_prior_out; const float* bb_prior_out;
  const float* w_prior_stats; const float* b_prior_stats;
  const float* w_post; const float* g_post; const float* bb_post;
  const float* w_post_stats; const float* b_post_stats;
  const float* initial_deter;
  float* out;
  // SINGLE-plane bf16 weights (hi only), unswizzled chunk images for global->VGPR loads.
  // Total 4.3 MB -> L2-resident per XCD. A-side stays 2-plane (hi+lo) in LDS.
  u16 *WgT3;    // 192 images (pc*6+np) x 8192 u16; R=256 rows x 32k. K=[deter512|h512]
  u16 *W2T3;    // 68  images (pc*4+np) x 8192 u16; K=[deter512|obs32]
  u16 *WsT3;    // 32  images (pc)      x 4096 u16; R=128, K=h2(1024)
  float *wpiT;  // [512][36] transposed w_prior_in
  float *deter0, *init_mean;
  int *segb, *segt0, *nact;
};

__device__ __forceinline__ float b2f(u16 u) {
  union { float f; u32 i; } v; v.i = ((u32)u) << 16; return v.f;
}
__device__ __forceinline__ u16 f2b(float f) {
  union { float f; u32 i; } v; v.f = f;
  u32 r = v.i + 0x7FFF + ((v.i >> 16) & 1);   // RNE
  return (u16)(r >> 16);
}
__device__ __forceinline__ float sigm(float x) { return 1.f / (1.f + __expf(-x)); }
__device__ __forceinline__ float splus(float x) { return x > 15.f ? x : log1pf(__expf(x)); }

// write hi/lo planes of logical (row i, col kk) into a 2-plane swizzled chunk buffer
__device__ __forceinline__ void awr2(u16* base, int i, int kk, u16 hi, u16 lo) {
  int o = (kk >> 5) << 11;
  int sw = ((i << 5) + (kk & 31)) ^ ((i & 7) << 3);
  base[o + sw] = hi;
  base[o + 1024 + sw] = lo;
}

// ---- prior_in head: h = silu(ln(x @ Wpi)); writes h planes (arow cols 544..1055) ----
__device__ __forceinline__ void h_from_x(const P& p, u16* arow, int i, float xv, int lane) {
  float xs[36];
  #pragma unroll
  for (int j = 0; j < 36; ++j) xs[j] = __shfl(xv, j, 64);
  float a0[8];
  #pragma unroll
  for (int c = 0; c < 8; ++c) {
    const float4* wp = (const float4*)(p.wpiT + (size_t)(lane + (c << 6)) * 36);
    float s = 0.f;
    #pragma unroll
    for (int t4 = 0; t4 < 9; ++t4) {
      float4 ww = wp[t4];
      s = fmaf(xs[4 * t4], ww.x, s); s = fmaf(xs[4 * t4 + 1], ww.y, s);
      s = fmaf(xs[4 * t4 + 2], ww.z, s); s = fmaf(xs[4 * t4 + 3], ww.w, s);
    }
    a0[c] = s;
  }
  float sm = 0.f, sq = 0.f;
  #pragma unroll
  for (int c = 0; c < 8; ++c) { sm += a0[c]; sq += a0[c] * a0[c]; }
  #pragma unroll
  for (int o = 32; o; o >>= 1) { sm += __shfl_xor(sm, o); sq += __shfl_xor(sq, o); }
  float m = sm * (1.f / 512.f);
  float rs = rsqrtf(sq * (1.f / 512.f) - m * m + 1e-3f);
  #pragma unroll
  for (int c = 0; c < 8; ++c) {
    int col = lane + (c << 6);
    float v = (a0[c] - m) * rs * p.g_prior_in[col] + p.bb_prior_in[col];
    v = v * sigm(v);
    u16 hi = f2b(v);
    awr2(arow, i, 544 + col, hi, f2b(v - b2f(hi)));
  }
}

// ================= prep kernels =================
__global__ void k_weights(P p) {
  const int E1 = 1024 * 1536, E2 = 544 * 1024, E3 = 1024 * 128, E4 = 36 * 512;
  const int total = E1 + E2 + E3 + E4;
  for (int idx = blockIdx.x * blockDim.x + threadIdx.x; idx < total;
       idx += gridDim.x * blockDim.x) {
    if (idx < E1) {                        // Wg
      int k = idx / 1536, n = idx - k * 1536;
      float w = (k < 512) ? p.w_gru[(512 + k) * 1536 + n] : p.w_gru[(k - 512) * 1536 + n];
      int np = n >> 8, r = n & 255, pc = k >> 5, kk = k & 31;
      p.WgT3[((size_t)(pc * 6 + np) << 13) + (r << 5) + kk] = f2b(w);
    } else if (idx < E1 + E2) {            // W2
      int t = idx - E1; int k = t >> 10, n = t & 1023;
      float w;
      if (k < 512) w = (n < 512) ? p.w_prior_out[k * 512 + n] : p.w_post[k * 512 + (n - 512)];
      else { int j = k - 512; w = (n >= 512 && j < 18) ? p.w_post[(512 + j) * 512 + (n - 512)] : 0.f; }
      int np = n >> 8, r = n & 255, pc = k >> 5, kk = k & 31;
      p.W2T3[((size_t)(pc * 4 + np) << 13) + (r << 5) + kk] = f2b(w);
    } else if (idx < E1 + E2 + E3) {       // Ws
      int t = idx - E1 - E2; int k = t >> 7, n = t & 127;
      float w;
      if (n < 64) w = (k < 512) ? p.w_prior_stats[k * 64 + n] : 0.f;
      else        w = (k >= 512) ? p.w_post_stats[(k - 512) * 64 + (n - 64)] : 0.f;
      int pc = k >> 5, kk = k & 31;
      p.WsT3[((size_t)pc << 12) + (n << 5) + kk] = f2b(w);
    } else {                               // wpiT transpose
      int t = idx - E1 - E2 - E3; int j = t >> 9, col = t & 511;
      p.wpiT[col * 36 + j] = p.w_prior_in[j * 512 + col];
    }
  }
}

__global__ void k_init_state(P p) {
  __shared__ float d0s[512], tmp[512], red[256];
  int tid = threadIdx.x;
  for (int n = tid; n < 512; n += 256) { d0s[n] = tanhf(p.initial_deter[n]); p.deter0[n] = d0s[n]; }
  __syncthreads();
  for (int n = tid; n < 512; n += 256) {
    float s = 0.f;
    for (int d = 0; d < 512; ++d) s = fmaf(d0s[d], p.w_prior_out[d * 512 + n], s);
    tmp[n] = s;
  }
  __syncthreads();
  float ls = 0.f, lq = 0.f;
  for (int n = tid; n < 512; n += 256) { ls += tmp[n]; lq += tmp[n] * tmp[n]; }
  red[tid] = ls; __syncthreads();
  for (int s = 128; s; s >>= 1) { if (tid < s) red[tid] += red[tid + s]; __syncthreads(); }
  float m = red[0] * (1.f / 512.f); __syncthreads();
  red[tid] = lq; __syncthreads();
  for (int s = 128; s; s >>= 1) { if (tid < s) red[tid] += red[tid + s]; __syncthreads(); }
  float rs = rsqrtf(red[0] * (1.f / 512.f) - m * m + 1e-3f); __syncthreads();
  for (int n = tid; n < 512; n += 256) {
    float h = (tmp[n] - m) * rs * p.g_prior_out[n] + p.bb_prior_out[n];
    tmp[n] = h * sigm(h);
  }
  __syncthreads();
  if (tid < 32) {
    float s = 0.f;
    for (int d = 0; d < 512; ++d) s = fmaf(tmp[d], p.w_prior_stats[d * 64 + tid], s);
    p.init_mean[tid] = s + p.b_prior_stats[tid];
  }
}

__global__ void k_segments(P p) {
  __shared__ int hist[257], off[258], cur[257];
  int tid = threadIdx.x;
  for (int i = tid; i < 257; i += 256) hist[i] = 0;
  __syncthreads();
  int b = tid;
  { int t = 0;
    while (t < TT) {
      int t0 = t; t++;
      while (t < TT && p.is_first[b * TT + t] == 0) t++;
      atomicAdd(&hist[t - t0], 1);
    } }
  __syncthreads();
  if (tid == 0) {
    int run = 0;
    for (int len = 256; len >= 0; --len) { off[len] = run; run += hist[len]; }
  }
  __syncthreads();
  for (int i = tid; i < 257; i += 256) { cur[i] = off[i]; p.nact[i] = off[i]; }
  __syncthreads();
  { int t = 0;
    while (t < TT) {
      int t0 = t; t++;
      while (t < TT && p.is_first[b * TT + t] == 0) t++;
      int idx = atomicAdd(&cur[t - t0], 1);
      p.segb[idx] = b; p.segt0[idx] = t0;
    } }
}

// ---- barrier-free GEMM pass: C(32 x NI*16 per wave) += A(LDS, 2-plane) * W^T ----
// Single-plane W global->VGPR, 8-set rotation (cover 7 steps); products ah*W + al*W.
template<int NI, int NSTEPS, int JAT>
__device__ __forceinline__ void gemm_nb(
    const u16* aLds, const u16* __restrict__ wBase, int wStrideU16,
    int wave, int quad, int l15, int xr, f32x4 (&acc)[2][NI]) {
  const u16* wq = wBase + (((wave * (NI * 16) + l15) << 5) + (quad << 3));
  bf16x8 H[8][NI];
  auto ld = [&](int st, int s) {
    const u16* q = wq + (size_t)st * wStrideU16;
    #pragma unroll
    for (int ni = 0; ni < NI; ++ni)
      H[s][ni] = *(const bf16x8*)(q + (ni << 9));
  };
  auto cp = [&](int st, int s) {
    int apc = st + (st >= JAT ? 1 : 0);
    const u16* A = aLds + (apc << 11);
    bf16x8 ah[2], al[2];
    #pragma unroll
    for (int mi = 0; mi < 2; ++mi) {
      int off = ((((mi << 4) + l15) << 5) + (quad << 3)) ^ xr;
      ah[mi] = *(const bf16x8*)&A[off];
      al[mi] = *(const bf16x8*)&A[off + 1024];
    }
    #pragma unroll
    for (int ni = 0; ni < NI; ++ni)
      #pragma unroll
      for (int mi = 0; mi < 2; ++mi) {
        acc[mi][ni] = __builtin_amdgcn_mfma_f32_16x16x32_bf16(ah[mi], H[s][ni], acc[mi][ni], 0, 0, 0);
        acc[mi][ni] = __builtin_amdgcn_mfma_f32_16x16x32_bf16(al[mi], H[s][ni], acc[mi][ni], 0, 0, 0);
      }
  };
  #pragma unroll
  for (int s = 0; s < 7; ++s) if (s < NSTEPS) ld(s, s);
  #pragma unroll
  for (int st = 0; st < NSTEPS; ++st) {
    if (st + 7 < NSTEPS) ld(st + 7, (st + 7) & 7);
    cp(st, st & 7);
  }
}

// ================= main persistent kernel: 8 waves, free-running static schedule =================
__global__ void __launch_bounds__(BDIM, 1) k_main(P p) {
  __shared__ u16 arow[67584];         // 33 chunks x 2048 u16: deter pc0-15, obs pc16, h pc17-32
  __shared__ float lnscr[8][32][4];
  __shared__ float stochs[1024];
  __shared__ int orowt[32];
  const int tid = threadIdx.x;
  const int wave = tid >> 6, lane = tid & 63, quad = lane >> 4, l15 = lane & 15;
  const int xr = (l15 & 7) << 3;
  u16* h2l = arow + 34816;            // phase E/F: 32 single-plane chunks x 1024 u16
  const int blk = blockIdx.x;
  const int S_total = p.nact[0];
  const int ntiles = (S_total + 31) >> 5;
  const int gmax = (ntiles + 255) & ~255;

  for (int g = blk; g < gmax; g += GRID) {
    int rr_ = g >> 8, w = g & 255;
    int x = w & 7; if (rr_ & 1) x = 7 - x;
    int t = (rr_ << 8) + (x << 5) + ((w >> 3) & 31);
    if (t >= ntiles) continue;
    int row0 = t << 5;
    int nr0 = S_total - row0; if (nr0 > 32) nr0 = 32;

    for (int k = 0;; ++k) {
      int Mk = p.nact[k] - row0; if (Mk > nr0) Mk = nr0;
      if (Mk <= 0) break;

      // ---- A: orowt + state init (k==0) + obs planes + prior_in head ----
      if (tid < 32)
        orowt[tid] = (tid < Mk) ? (p.segb[row0 + tid] * TT + p.segt0[row0 + tid] + k) : -1;
      for (int i = wave; i < Mk; i += 8) {
        int gi = row0 + i;
        int b = p.segb[gi], t0 = p.segt0[gi];
        float xv = 0.f;
        if (k == 0) {
          #pragma unroll
          for (int c = 0; c < 8; ++c) {
            int d = lane + (c << 6);
            float v = p.deter0[d];
            u16 hi = f2b(v);
            awr2(arow, i, d, hi, f2b(v - b2f(hi)));
          }
          int ff = p.is_first[b * TT + t0];
          if (lane < 32) xv = p.init_mean[lane];
          else if (lane < 36) xv = (ff > 0) ? 0.f : p.action[((size_t)b * TT + t0) * 4 + (lane - 32)];
        } else {
          if (lane < 32) xv = stochs[(i << 5) + lane];
          else if (lane < 36) xv = p.action[((size_t)b * TT + t0 + k) * 4 + (lane - 32)];
        }
        int tc = t0 + k;
        if (lane < 32) {
          float ov = (lane < 18) ? p.obs[((size_t)b * TT + tc) * 18 + lane] : 0.f;
          u16 hi = f2b(ov);
          awr2(arow, i, 512 + lane, hi, f2b(ov - b2f(hi)));
        }
        h_from_x(p, arow, i, xv, lane);
      }
      __syncthreads();

      // ---- B: gates = arow[deter|h] @ Wg  (6 passes, K=1024, barrier-free) ----
      f32x4 acc[6][2][2];
      #pragma unroll
      for (int np = 0; np < 6; ++np) {
        #pragma unroll
        for (int mi = 0; mi < 2; ++mi)
          #pragma unroll
          for (int ni = 0; ni < 2; ++ni) acc[np][mi][ni] = f32x4{0.f, 0.f, 0.f, 0.f};
        gemm_nb<2, 32, 16>(arow, p.WgT3 + np * 8192, 6 * 8192,
                           wave, quad, l15, xr, acc[np]);
      }
      __syncthreads();   // all waves done reading deter/h planes

      // ---- C (fused): cross-wave LN(gates) -> GRU -> deter planes + out ----
      {
        float smv[2][4], sqv[2][4];
        #pragma unroll
        for (int mi = 0; mi < 2; ++mi)
          #pragma unroll
          for (int rg = 0; rg < 4; ++rg) { smv[mi][rg] = 0.f; sqv[mi][rg] = 0.f; }
        #pragma unroll
        for (int np = 0; np < 6; ++np)
          #pragma unroll
          for (int mi = 0; mi < 2; ++mi)
            #pragma unroll
            for (int ni = 0; ni < 2; ++ni)
              #pragma unroll
              for (int rg = 0; rg < 4; ++rg) {
                float v = acc[np][mi][ni][rg];
                smv[mi][rg] += v; sqv[mi][rg] += v * v;
              }
        #pragma unroll
        for (int mi = 0; mi < 2; ++mi)
          #pragma unroll
          for (int rg = 0; rg < 4; ++rg) {
            float s = smv[mi][rg], qv = sqv[mi][rg];
            #pragma unroll
            for (int o = 1; o < 16; o <<= 1) { s += __shfl_xor(s, o); qv += __shfl_xor(qv, o); }
            smv[mi][rg] = s; sqv[mi][rg] = qv;
          }
        if (l15 == 0) {
          #pragma unroll
          for (int mi = 0; mi < 2; ++mi)
            #pragma unroll
            for (int rg = 0; rg < 4; ++rg) {
              int row = (mi << 4) + (quad << 2) + rg;
              lnscr[wave][row][0] = smv[mi][rg];
              lnscr[wave][row][1] = sqv[mi][rg];
            }
        }
        __syncthreads();
        #pragma unroll
        for (int mi = 0; mi < 2; ++mi)
          #pragma unroll
          for (int rg = 0; rg < 4; ++rg) {
            int row = (mi << 4) + (quad << 2) + rg;
            float a0 = 0.f, a1 = 0.f;
            #pragma unroll
            for (int w2 = 0; w2 < 8; ++w2) { a0 += lnscr[w2][row][0]; a1 += lnscr[w2][row][1]; }
            float m_ = a0 * (1.f / 1536.f);
            smv[mi][rg] = m_;
            sqv[mi][rg] = rsqrtf(a1 * (1.f / 1536.f) - m_ * m_ + 1e-3f);
          }
        #pragma unroll
        for (int hh = 0; hh < 2; ++hh)
          #pragma unroll
          for (int ni = 0; ni < 2; ++ni) {
            int dcol = (hh << 8) + (wave << 5) + (ni << 4) + l15;
            float gR = p.g_gru[dcol], gC = p.g_gru[512 + dcol], gU = p.g_gru[1024 + dcol];
            float bR = p.bb_gru[dcol], bC = p.bb_gru[512 + dcol], bU = p.bb_gru[1024 + dcol];
            int pcD = dcol >> 5, kkD = dcol & 31;
            #pragma unroll
            for (int mi = 0; mi < 2; ++mi)
              #pragma unroll
              for (int rg = 0; rg < 4; ++rg) {
                int row = (mi << 4) + (quad << 2) + rg;
                float m_ = smv[mi][rg], rs_ = sqv[mi][rg];
                float vr = (acc[hh][mi][ni][rg] - m_) * rs_ * gR + bR;
                float vc = (acc[2 + hh][mi][ni][rg] - m_) * rs_ * gC + bC;
                float vu = (acc[4 + hh][mi][ni][rg] - m_) * rs_ * gU + bU;
                float r_ = sigm(vr), u_ = sigm(vu - 1.f);
                float rc = r_ * vc, cand = rc * sigm(rc);
                int ab = (pcD << 11) + (((row << 5) + kkD) ^ ((row & 7) << 3));
                float dp = b2f(arow[ab]) + b2f(arow[ab + 1024]);
                float dn = u_ * cand + (1.f - u_) * dp;
                u16 hi = f2b(dn);
                arow[ab] = hi; arow[ab + 1024] = f2b(dn - b2f(hi));
                int ot = orowt[row];
                if (ot >= 0) {
                  float* orow = p.out + (size_t)ot * 1216;
                  orow[dcol] = dn; orow[608 + dcol] = dn;
                }
              }
          }
      }
      __syncthreads();

      // ---- D: hraw = arow[deter|obs] @ W2  (4 passes, K=544, barrier-free) ----
      f32x4 dac[4][2][2];
      #pragma unroll
      for (int np = 0; np < 4; ++np) {
        #pragma unroll
        for (int mi = 0; mi < 2; ++mi)
          #pragma unroll
          for (int ni = 0; ni < 2; ++ni) dac[np][mi][ni] = f32x4{0.f, 0.f, 0.f, 0.f};
        gemm_nb<2, 17, 100>(arow, p.W2T3 + np * 8192, 4 * 8192,
                            wave, quad, l15, xr, dac[np]);
      }

      // ---- E (fused): two cross-wave LNs + silu -> h2 single-plane into LDS ----
      {
        float sP[2][4], qP[2][4], sQ[2][4], qQ[2][4];
        #pragma unroll
        for (int mi = 0; mi < 2; ++mi)
          #pragma unroll
          for (int rg = 0; rg < 4; ++rg) { sP[mi][rg]=0.f; qP[mi][rg]=0.f; sQ[mi][rg]=0.f; qQ[mi][rg]=0.f; }
        #pragma unroll
        for (int np = 0; np < 4; ++np)
          #pragma unroll
          for (int mi = 0; mi < 2; ++mi)
            #pragma unroll
            for (int ni = 0; ni < 2; ++ni)
              #pragma unroll
              for (int rg = 0; rg < 4; ++rg) {
                float v = dac[np][mi][ni][rg];
                if (np < 2) { sP[mi][rg] += v; qP[mi][rg] += v * v; }
                else        { sQ[mi][rg] += v; qQ[mi][rg] += v * v; }
              }
        #pragma unroll
        for (int mi = 0; mi < 2; ++mi)
          #pragma unroll
          for (int rg = 0; rg < 4; ++rg) {
            float a0 = sP[mi][rg], a1 = qP[mi][rg], a2 = sQ[mi][rg], a3 = qQ[mi][rg];
            #pragma unroll
            for (int o = 1; o < 16; o <<= 1) {
              a0 += __shfl_xor(a0, o); a1 += __shfl_xor(a1, o);
              a2 += __shfl_xor(a2, o); a3 += __shfl_xor(a3, o);
            }
            sP[mi][rg] = a0; qP[mi][rg] = a1; sQ[mi][rg] = a2; qQ[mi][rg] = a3;
          }
        if (l15 == 0) {
          #pragma unroll
          for (int mi = 0; mi < 2; ++mi)
            #pragma unroll
            for (int rg = 0; rg < 4; ++rg) {
              int row = (mi << 4) + (quad << 2) + rg;
              lnscr[wave][row][0] = sP[mi][rg]; lnscr[wave][row][1] = qP[mi][rg];
              lnscr[wave][row][2] = sQ[mi][rg]; lnscr[wave][row][3] = qQ[mi][rg];
            }
        }
        __syncthreads();   // all waves finished D; h-region rewrite now safe
        float mP[2][4], rP[2][4], mQ[2][4], rQ[2][4];
        #pragma unroll
        for (int mi = 0; mi < 2; ++mi)
          #pragma unroll
          for (int rg = 0; rg < 4; ++rg) {
            int row = (mi << 4) + (quad << 2) + rg;
            float a0 = 0.f, a1 = 0.f, a2 = 0.f, a3 = 0.f;
            #pragma unroll
            for (int w2 = 0; w2 < 8; ++w2) {
              a0 += lnscr[w2][row][0]; a1 += lnscr[w2][row][1];
              a2 += lnscr[w2][row][2]; a3 += lnscr[w2][row][3];
            }
            mP[mi][rg] = a0 * (1.f / 512.f);
            rP[mi][rg] = rsqrtf(a1 * (1.f / 512.f) - mP[mi][rg] * mP[mi][rg] + 1e-3f);
            mQ[mi][rg] = a2 * (1.f / 512.f);
            rQ[mi][rg] = rsqrtf(a3 * (1.f / 512.f) - mQ[mi][rg] * mQ[mi][rg] + 1e-3f);
          }
        #pragma unroll
        for (int np = 0; np < 4; ++np) {
          const int half = np >> 1;
          #pragma unroll
          for (int ni = 0; ni < 2; ++ni) {
            int col = (np << 8) + (wave << 5) + (ni << 4) + l15;
            int c5 = col & 511;
            float gv = half ? p.g_post[c5] : p.g_prior_out[c5];
            float bv = half ? p.bb_post[c5] : p.bb_prior_out[c5];
            int pcH = col >> 5, kkH = col & 31;
            #pragma unroll
            for (int mi = 0; mi < 2; ++mi)
              #pragma unroll
              for (int rg = 0; rg < 4; ++rg) {
                int row = (mi << 4) + (quad << 2) + rg;
                float m_ = half ? mQ[mi][rg] : mP[mi][rg];
                float rs_ = half ? rQ[mi][rg] : rP[mi][rg];
                float xx = (dac[np][mi][ni][rg] - m_) * rs_ * gv + bv;
                xx = xx * sigm(xx);
                h2l[(pcH << 10) + (((row << 5) + kkH) ^ ((row & 7) << 3))] = f2b(xx);
              }
          }
        }
      }
      __syncthreads();   // h2 in LDS visible to all waves

      // ---- F: stats = h2l @ Ws (32 steps, LDS A single-plane, single-plane W, 8-set) ----
      {
        const u16* wqF = p.WsT3 + (((wave << 4) + l15) << 5) + (quad << 3);
        f32x4 fac[2];
        fac[0] = f32x4{0.f, 0.f, 0.f, 0.f};
        fac[1] = f32x4{0.f, 0.f, 0.f, 0.f};
        bf16x8 FH[8];
        auto ldF = [&](int st, int s) {
          FH[s] = *(const bf16x8*)(wqF + (st << 12));
        };
        auto cpF = [&](int st, int s) {
          const u16* A = h2l + (st << 10);
          #pragma unroll
          for (int mi = 0; mi < 2; ++mi) {
            int off = ((((mi << 4) + l15) << 5) + (quad << 3)) ^ xr;
            bf16x8 ah = *(const bf16x8*)&A[off];
            fac[mi] = __builtin_amdgcn_mfma_f32_16x16x32_bf16(ah, FH[s], fac[mi], 0, 0, 0);
          }
        };
        #pragma unroll
        for (int s = 0; s < 7; ++s) ldF(s, s);
        #pragma unroll
        for (int st = 0; st < 32; ++st) {
          if (st + 7 < 32) ldF(st + 7, (st + 7) & 7);
          cpF(st, st & 7);
        }
        #pragma unroll
        for (int mi = 0; mi < 2; ++mi)
          #pragma unroll
          for (int rg = 0; rg < 4; ++rg) {
            int i = (mi << 4) + (quad << 2) + rg;
            int col = (wave << 4) + l15;
            if (i < Mk) {
              float v = fac[mi][rg];
              int ot = orowt[i];
              float* orow = p.out + (size_t)ot * 1216;
              if (col < 32) {
                v += p.b_prior_stats[col];
                orow[1120 + col] = v; orow[1152 + col] = v;
              } else if (col < 64) {
                v = splus(v + p.b_prior_stats[col]) + 0.1f;
                orow[1184 + col - 32] = v;
              } else if (col < 96) {
                v += p.b_post_stats[col - 64];
                orow[512 + col - 64] = v; orow[544 + col - 64] = v;
                stochs[(i << 5) + (col - 64)] = v;
              } else {
                v = splus(v + p.b_post_stats[col - 64]) + 0.1f;
                orow[576 + col - 96] = v;
              }
            }
          }
      }
      __syncthreads();
    }
  }
}

extern "C" void kernel_launch(void* const* d_in, const int* in_sizes, int n_in,
                              void* d_out, int out_size, void* d_ws, size_t ws_size,
                              hipStream_t stream) {
  P p;
  p.obs = (const float*)d_in[0];
  p.action = (const float*)d_in[1];
  p.is_first = (const int*)d_in[2];
  p.w_prior_in = (const float*)d_in[3];
  p.g_prior_in = (const float*)d_in[4];
  p.bb_prior_in = (const float*)d_in[5];
  p.w_gru = (const float*)d_in[6];
  p.g_gru = (const float*)d_in[7];
  p.bb_gru = (const float*)d_in[8];
  p.w_prior_out = (const float*)d_in[9];
  p.g_prior_out = (const float*)d_in[10];
  p.bb_prior_out = (const float*)d_in[11];
  p.w_prior_stats = (const float*)d_in[12];
  p.b_prior_stats = (const float*)d_in[13];
  p.w_post = (const float*)d_in[14];
  p.g_post = (const float*)d_in[15];
  p.bb_post = (const float*)d_in[16];
  p.w_post_stats = (const float*)d_in[17];
  p.b_post_stats = (const float*)d_in[18];
  p.initial_deter = (const float*)d_in[19];
  p.out = (float*)d_out;

  char* w = (char*)d_ws;
  auto alloc = [&](size_t bytes) -> char* {
    char* r = w; w += (bytes + 255) & ~(size_t)255; return r;
  };
  p.WgT3 = (u16*)alloc((size_t)192 * 8192 * 2);
  p.W2T3 = (u16*)alloc((size_t)68 * 8192 * 2);
  p.WsT3 = (u16*)alloc((size_t)32 * 4096 * 2);
  p.wpiT = (float*)alloc((size_t)512 * 36 * 4);
  p.deter0 = (float*)alloc(512 * 4);
  p.init_mean = (float*)alloc(32 * 4);
  p.segb = (int*)alloc((size_t)65536 * 4);
  p.segt0 = (int*)alloc((size_t)65536 * 4);
  p.nact = (int*)alloc(257 * 4);

  k_weights<<<dim3(256), dim3(256), 0, stream>>>(p);
  k_init_state<<<dim3(1), dim3(256), 0, stream>>>(p);
  k_segments<<<dim3(1), dim3(256), 0, stream>>>(p);
  k_main<<<dim3(GRID), dim3(BDIM), 0, stream>>>(p);
}